// Round 1
// baseline (28.889 us; speedup 1.0000x reference)
//
#include <hip/hip_runtime.h>
#include <float.h>
#include <math.h>

#define V 50000
#define D 300
#define Z 128
#define C 10
#define TWOD 600

// ---------------- ws layout (float units) ----------------
// [0]        int   cidx
// [1]        float klsum
// [2..18)    float gather[16]   (C=10 used)
// [32..288)  float raw[256]     raw[z]=u_z raw[128+z]=sig_raw_z
// [288..544) float bm[256]      per-block lse max
// [544..800) float bs[256]      per-block lse sum
// total 3200 bytes

__global__ void k_find(const float* __restrict__ cw, int* __restrict__ cidx) {
    int v = blockIdx.x * blockDim.x + threadIdx.x;
    if (v < V && cw[v] != 0.0f) *cidx = v;
}

// 64 blocks x 256. Each block: (redundantly) build summed[600] in LDS via
// one-hot gathers, then 4 row-dots (one per wave) of W_mu/W_sig vs summed.
__global__ void k_encode(const float* __restrict__ E,
                         const int* __restrict__ idxs,
                         const float* __restrict__ Wmu, const float* __restrict__ bmu,
                         const float* __restrict__ Wsig, const float* __restrict__ bsig,
                         const int* __restrict__ cidx_p,
                         float* __restrict__ raw) {
    __shared__ float summed[TWOD];
    __shared__ int sidx[C];
    int tid = threadIdx.x;
    if (tid < C) sidx[tid] = idxs[tid];
    int cidx = *cidx_p;
    __syncthreads();
    for (int d = tid; d < D; d += blockDim.x) {
        float ce = E[(size_t)d * V + cidx];
        summed[d] = (float)C * fmaxf(ce, 0.0f);          // relu(ce) summed over C rows
        float acc = 0.0f;
        #pragma unroll
        for (int c = 0; c < C; ++c) {
            float cw = E[(size_t)d * V + sidx[c]];
            acc += fmaxf(cw, 0.0f);
        }
        summed[D + d] = acc;
    }
    __syncthreads();
    int wave = tid >> 6, lane = tid & 63;
    int r = blockIdx.x * 4 + wave;                        // 0..255
    int z = r & (Z - 1);
    const float* Wrow;
    float bias;
    if (r < Z) { Wrow = Wmu  + (size_t)z * TWOD; bias = bmu[z]; }
    else       { Wrow = Wsig + (size_t)z * TWOD; bias = bsig[z]; }
    float acc = 0.0f;
    for (int k = lane; k < TWOD; k += 64) acc += Wrow[k] * summed[k];
    #pragma unroll
    for (int off = 32; off; off >>= 1) acc += __shfl_xor(acc, off);
    if (lane == 0) raw[r] = acc + bias;
}

__device__ __forceinline__ float softplusf(float x) {
    return log1pf(expf(-fabsf(x))) + fmaxf(x, 0.0f);
}

// 196 blocks x 256. Phase 0: rebuild z[128] in LDS from raw (block 0 also
// computes KL sum). Phase 1: one logit per thread (W_gen row dot z), gather
// the C requested logits, online (m,s) logsumexp reduce per block.
__global__ void k_logits(const float* __restrict__ Wgen, const float* __restrict__ bgen,
                         const float* __restrict__ eps,
                         const float* __restrict__ psig,
                         const int* __restrict__ idxs,
                         const int* __restrict__ cidx_p,
                         const float* __restrict__ raw,
                         float* __restrict__ gather, float* __restrict__ klsum,
                         float* __restrict__ bm, float* __restrict__ bs) {
    __shared__ __align__(16) float zsh[Z];
    __shared__ int sidx[C];
    __shared__ float red_m[4], red_s[4];
    __shared__ float klred[2];
    int tid = threadIdx.x;
    if (tid < C) sidx[tid] = idxs[tid];
    if (tid < Z) {
        float u  = raw[tid];
        float sr = raw[Z + tid];
        float s  = softplusf(sr);
        zsh[tid] = u + eps[tid] * s;
        if (blockIdx.x == 0) {
            int cidx = *cidx_p;
            float zs = softplusf(psig[(size_t)tid * V + cidx]);
            float kl = logf(zs / s) + (s * s + (u - zs) * (u - zs)) / (2.0f * zs * zs) - 0.5f;
            #pragma unroll
            for (int off = 32; off; off >>= 1) kl += __shfl_xor(kl, off);
            if ((tid & 63) == 0) klred[tid >> 6] = kl;
        }
    }
    __syncthreads();
    if (blockIdx.x == 0 && tid == 0) *klsum = klred[0] + klred[1];

    int v = blockIdx.x * blockDim.x + tid;
    float m = -FLT_MAX, ssum = 0.0f;
    if (v < V) {
        const float4* w  = (const float4*)(Wgen + (size_t)v * Z);
        const float4* zz = (const float4*)zsh;
        float acc = 0.0f;
        #pragma unroll
        for (int k = 0; k < Z / 4; ++k) {
            float4 a = w[k], b = zz[k];
            acc += a.x * b.x + a.y * b.y + a.z * b.z + a.w * b.w;
        }
        float logit = acc + bgen[v];
        #pragma unroll
        for (int c = 0; c < C; ++c)
            if (v == sidx[c]) gather[c] = logit;
        m = logit; ssum = 1.0f;
    }
    #pragma unroll
    for (int off = 32; off; off >>= 1) {
        float m2 = __shfl_xor(m, off);
        float s2 = __shfl_xor(ssum, off);
        float M  = fmaxf(m, m2);
        ssum = ssum * expf(m - M) + s2 * expf(m2 - M);
        m = M;
    }
    int wave = tid >> 6, lane = tid & 63;
    if (lane == 0) { red_m[wave] = m; red_s[wave] = ssum; }
    __syncthreads();
    if (tid == 0) {
        float M = red_m[0], S = red_s[0];
        #pragma unroll
        for (int w2 = 1; w2 < 4; ++w2) {
            float m2 = red_m[w2], s2 = red_s[w2];
            float Mn = fmaxf(M, m2);
            S = S * expf(M - Mn) + s2 * expf(m2 - Mn);
            M = Mn;
        }
        bm[blockIdx.x] = M;
        bs[blockIdx.x] = S;
    }
}

__global__ void k_final(const float* __restrict__ bm, const float* __restrict__ bs,
                        const float* __restrict__ gather, const float* __restrict__ klsum,
                        int nblocks, float* __restrict__ out) {
    __shared__ float red_m[4], red_s[4];
    int tid = threadIdx.x;
    float m = -FLT_MAX, s = 0.0f;
    if (tid < nblocks) { m = bm[tid]; s = bs[tid]; }
    #pragma unroll
    for (int off = 32; off; off >>= 1) {
        float m2 = __shfl_xor(m, off), s2 = __shfl_xor(s, off);
        float M = fmaxf(m, m2);
        s = s * expf(m - M) + s2 * expf(m2 - M);
        m = M;
    }
    int wave = tid >> 6, lane = tid & 63;
    if (lane == 0) { red_m[wave] = m; red_s[wave] = s; }
    __syncthreads();
    if (tid == 0) {
        float M = red_m[0], S = red_s[0];
        #pragma unroll
        for (int w = 1; w < 4; ++w) {
            float m2 = red_m[w], s2 = red_s[w];
            float Mn = fmaxf(M, m2);
            S = S * expf(M - Mn) + s2 * expf(m2 - Mn);
            M = Mn;
        }
        float lse = M + logf(S);
        float g = 0.0f;
        #pragma unroll
        for (int c = 0; c < C; ++c) g += gather[c];
        out[0] = g - (float)C * lse - *klsum;
    }
}

extern "C" void kernel_launch(void* const* d_in, const int* in_sizes, int n_in,
                              void* d_out, int out_size, void* d_ws, size_t ws_size,
                              hipStream_t stream) {
    const float* center = (const float*)d_in[0];
    // d_in[1] context_words: one-hot of idxs -> unused (exact gather via idxs)
    const int*   idxs   = (const int*)d_in[2];
    const float* eps    = (const float*)d_in[3];
    const float* E      = (const float*)d_in[4];
    const float* Wmu    = (const float*)d_in[5];
    const float* bmu    = (const float*)d_in[6];
    const float* Wsig   = (const float*)d_in[7];
    const float* bsig   = (const float*)d_in[8];
    // d_in[9] prior_mean: dead in reference
    const float* psig   = (const float*)d_in[10];
    const float* Wgen   = (const float*)d_in[11];
    const float* bgen   = (const float*)d_in[12];

    float* ws     = (float*)d_ws;
    int*   cidx   = (int*)ws;
    float* klsum  = ws + 1;
    float* gather = ws + 2;
    float* raw    = ws + 32;
    float* bm     = ws + 288;
    float* bs     = ws + 544;
    float* out    = (float*)d_out;

    int nb = (V + 255) / 256;  // 196
    k_find  <<<nb, 256, 0, stream>>>(center, cidx);
    k_encode<<<64, 256, 0, stream>>>(E, idxs, Wmu, bmu, Wsig, bsig, cidx, raw);
    k_logits<<<nb, 256, 0, stream>>>(Wgen, bgen, eps, psig, idxs, cidx, raw,
                                     gather, klsum, bm, bs);
    k_final <<<1, 256, 0, stream>>>(bm, bs, gather, klsum, nb, out);
}